// Round 5
// baseline (223.924 us; speedup 1.0000x reference)
//
#include <hip/hip_runtime.h>
#include <hip/hip_bf16.h>

// Problem dims (fixed by reference setup_inputs)
#define BB 4
#define SS 1024
#define DD 1024
#define HH 16
#define HD 64
#define MM (BB*SS)   // 4096 rows

// Session journal:
// Prev session: inputs fp32, out fp32; no-max softmax safe (masked keys
// expf(s-1e9)==0); XOR chunk swizzle kills GEMM LDS bank conflicts.
// R1: 128x128 tile REGRESSED (44.5us, MfmaUtil 22%) - latency-exposure-bound.
// R4: explicit dbuf REGRESSED (47.4us, MfmaUtil 20%): __syncthreads drains
//     vmcnt(0) including the fresh prefetch -> no hiding, +LDS cost.
//     Lesson (==guide m218): only COUNTED vmcnt pipelines; drain-0 never.
// R5: revert GEMMs to round-0 2-barrier 128x64 (proven ~40us qkv) and
//     DELETE convall's q/k/v pass: gemm_qkv A-staging now loads fp32
//     directly (float4 x2 -> cvt -> ds_write_b128, same swizzled layout).
//     Weights converted by a tiny convw kernel (8MB). Saves ~12us + 75MB.

typedef __bf16 bf16x8 __attribute__((ext_vector_type(8)));
typedef __bf16 bf16x4 __attribute__((ext_vector_type(4)));
typedef float  f32x4  __attribute__((ext_vector_type(4)));

// ---------------------------------------------------------------------------
// Padding mask -> float addend (-1e9 padded, 0 otherwise); format-sniffed.
// ---------------------------------------------------------------------------
__global__ __launch_bounds__(256) void expand_mask(const void* __restrict__ pmraw,
                                                   float* __restrict__ madd,
                                                   int n)
{
    const unsigned char* bytes = (const unsigned char*)pmraw;
    __shared__ int isbool;
    if (threadIdx.x == 0) isbool = 0;
    __syncthreads();
    int flag = 0;
    for (int idx = threadIdx.x; idx < n; idx += 256) {
        if ((idx & 3) && bytes[idx]) flag = 1;
    }
    if (flag) atomicOr(&isbool, 1);
    __syncthreads();
    int i = blockIdx.x * 256 + threadIdx.x;
    if (i < n) {
        int v = isbool ? (int)bytes[i] : ((const int*)pmraw)[i];
        madd[i] = (v != 0) ? -1e9f : 0.0f;
    }
}

// ---------------------------------------------------------------------------
// Weights-only fp32->bf16 convert (q/k/v conversion is fused into gemm_qkv).
// grid (1024, 4): y selects the weight, x*256*4 elements of 1M each.
// ---------------------------------------------------------------------------
__global__ __launch_bounds__(256) void convw(const float* __restrict__ Wq,
                                             const float* __restrict__ Wk,
                                             const float* __restrict__ Wv,
                                             const float* __restrict__ Wo,
                                             __bf16* __restrict__ Wqb,
                                             __bf16* __restrict__ Wkb,
                                             __bf16* __restrict__ Wvb,
                                             __bf16* __restrict__ Wob)
{
    const float* s; __bf16* d;
    const int wsel = blockIdx.y;
    if (wsel == 0)      { s = Wq; d = Wqb; }
    else if (wsel == 1) { s = Wk; d = Wkb; }
    else if (wsel == 2) { s = Wv; d = Wvb; }
    else                { s = Wo; d = Wob; }
    const int i = (blockIdx.x * 256 + threadIdx.x) * 4;
    float4 x = *(const float4*)(s + i);
    bf16x4 o;
    o[0] = (__bf16)x.x; o[1] = (__bf16)x.y;
    o[2] = (__bf16)x.z; o[3] = (__bf16)x.w;
    *(bf16x4*)(d + i) = o;
}

// ---------------------------------------------------------------------------
// Fused QKV MFMA GEMM, 128x64 tile, BK=64, M-major grid, round-0 2-barrier
// structure. A is read DIRECTLY from fp32 q/k/v: 2x float4 load -> cvt ->
// ds_write_b128 into the same XOR-swizzled LDS layout (reg-staging CAN hit
// the swizzled dest; global source column stays gcol-permuted so the
// COMPUTE read path is unchanged). B (weights, bf16) uses global_load_lds.
// z==0 (Q): prescale 0.125. z==2 (V): store transposed VpT[n][m] (stride MM).
// ---------------------------------------------------------------------------
#define GM 128
#define GN 64
#define GK 64

__global__ __launch_bounds__(256) void gemm_qkv(const float* __restrict__ q,
                                                const float* __restrict__ k,
                                                const float* __restrict__ v,
                                                const __bf16* __restrict__ Wqb,
                                                const __bf16* __restrict__ Wkb,
                                                const __bf16* __restrict__ Wvb,
                                                __bf16* __restrict__ Qp,
                                                __bf16* __restrict__ Kp,
                                                __bf16* __restrict__ VpT)
{
    __shared__ __align__(16) __bf16 As[GM][GK];   // 16 KB
    __shared__ __align__(16) __bf16 Bs[GN][GK];   // 8 KB

    const float* A; const __bf16* W; __bf16* C;
    const int z = blockIdx.z;
    if (z == 0)      { A = q; W = Wqb; C = Qp;  }
    else if (z == 1) { A = k; W = Wkb; C = Kp;  }
    else             { A = v; W = Wvb; C = VpT; }

    const int tid  = threadIdx.x;
    const int lane = tid & 63;
    const int w    = tid >> 6;
    const int l15  = lane & 15;
    const int quad = lane >> 4;
    const int wr   = w >> 1;
    const int wc   = w & 1;

    const int m0 = blockIdx.x * GM;    // M-MAJOR: x is the m-tile
    const int n0 = blockIdx.y * GN;

    const int srow = tid >> 3;                       // 0..31
    const int scol = (tid & 7) * 8;                  // LDS column (lane-linear)
    const int gcol = (((tid & 7) ^ (srow & 7)) * 8); // swizzled GLOBAL column

    const float*  gA = A + (size_t)(m0 + srow) * DD + gcol;   // fp32 source
    const __bf16* gB = W + (size_t)(n0 + srow) * DD + gcol;

    f32x4 acc[4][2] = {};

    for (int k0 = 0; k0 < DD; k0 += GK) {
        __syncthreads();
        // B first (async gload_lds flies during A's load+cvt)
        #pragma unroll
        for (int c = 0; c < 2; ++c)
            __builtin_amdgcn_global_load_lds(
                (const __attribute__((address_space(1))) void*)(gB + (size_t)c * 32 * DD + k0),
                (__attribute__((address_space(3))) void*)(&Bs[c * 32 + srow][scol]), 16, 0, 0);
        // A: fp32 -> bf16 fused conversion (rows srow+32c keep srow&7 invariant)
        float4 xa[8];
        #pragma unroll
        for (int c = 0; c < 4; ++c) {
            xa[2*c]   = *(const float4*)(gA + (size_t)c * 32 * DD + k0);
            xa[2*c+1] = *(const float4*)(gA + (size_t)c * 32 * DD + k0 + 4);
        }
        #pragma unroll
        for (int c = 0; c < 4; ++c) {
            bf16x8 o;
            o[0] = (__bf16)xa[2*c].x;   o[1] = (__bf16)xa[2*c].y;
            o[2] = (__bf16)xa[2*c].z;   o[3] = (__bf16)xa[2*c].w;
            o[4] = (__bf16)xa[2*c+1].x; o[5] = (__bf16)xa[2*c+1].y;
            o[6] = (__bf16)xa[2*c+1].z; o[7] = (__bf16)xa[2*c+1].w;
            *(bf16x8*)&As[c * 32 + srow][scol] = o;
        }
        __syncthreads();

        #pragma unroll
        for (int ks = 0; ks < 2; ++ks) {
            const int cidx = ((ks * 4 + quad) ^ (l15 & 7)) * 8;  // swizzled chunk
            bf16x8 af[4], bf[2];
            #pragma unroll
            for (int mt = 0; mt < 4; ++mt)
                af[mt] = *(const bf16x8*)&As[wr * 64 + mt * 16 + l15][cidx];
            #pragma unroll
            for (int nt = 0; nt < 2; ++nt)
                bf[nt] = *(const bf16x8*)&Bs[wc * 32 + nt * 16 + l15][cidx];
            #pragma unroll
            for (int mt = 0; mt < 4; ++mt)
                #pragma unroll
                for (int nt = 0; nt < 2; ++nt)
                    acc[mt][nt] = __builtin_amdgcn_mfma_f32_16x16x32_bf16(
                        af[mt], bf[nt], acc[mt][nt], 0, 0, 0);
        }
    }

    if (z == 0) {
        #pragma unroll
        for (int mt = 0; mt < 4; ++mt)
            #pragma unroll
            for (int nt = 0; nt < 2; ++nt)
                #pragma unroll
                for (int r = 0; r < 4; ++r)
                    acc[mt][nt][r] *= 0.125f;     // fold softmax scale into Q
    }

    if (z == 2) {
        #pragma unroll
        for (int mt = 0; mt < 4; ++mt)
            #pragma unroll
            for (int nt = 0; nt < 2; ++nt) {
                bf16x4 o;
                #pragma unroll
                for (int r = 0; r < 4; ++r) o[r] = (__bf16)acc[mt][nt][r];
                const int n = n0 + wc * 32 + nt * 16 + l15;
                const int m = m0 + wr * 64 + mt * 16 + quad * 4;
                *(bf16x4*)&C[(size_t)n * MM + m] = o;
            }
    } else {
        #pragma unroll
        for (int mt = 0; mt < 4; ++mt)
            #pragma unroll
            for (int nt = 0; nt < 2; ++nt)
                #pragma unroll
                for (int r = 0; r < 4; ++r)
                    C[(size_t)(m0 + wr * 64 + mt * 16 + quad * 4 + r) * DD +
                      (n0 + wc * 32 + nt * 16 + l15)] = (__bf16)acc[mt][nt][r];
    }
}

// ---------------------------------------------------------------------------
// Wo GEMM: round-0 structure exactly (A=Op bf16 + B=Wob bf16, both via
// global_load_lds; single-buffer 2-barrier; swizzled; fp32 out; M-major).
// ---------------------------------------------------------------------------
__global__ __launch_bounds__(256) void gemm_wo(const __bf16* __restrict__ Ain,
                                               const __bf16* __restrict__ W,
                                               float* __restrict__ C)
{
    __shared__ __align__(16) __bf16 As[GM][GK];   // 16 KB
    __shared__ __align__(16) __bf16 Bs[GN][GK];   // 8 KB

    const int tid  = threadIdx.x;
    const int lane = tid & 63;
    const int w    = tid >> 6;
    const int l15  = lane & 15;
    const int quad = lane >> 4;
    const int wr   = w >> 1;
    const int wc   = w & 1;

    const int m0 = blockIdx.x * GM;    // M-MAJOR
    const int n0 = blockIdx.y * GN;

    const int srow = tid >> 3;
    const int scol = (tid & 7) * 8;
    const int gcol = (((tid & 7) ^ (srow & 7)) * 8);

    const __bf16* gA = Ain + (size_t)(m0 + srow) * DD + gcol;
    const __bf16* gB = W   + (size_t)(n0 + srow) * DD + gcol;

    f32x4 acc[4][2] = {};

    for (int k0 = 0; k0 < DD; k0 += GK) {
        __syncthreads();
        #pragma unroll
        for (int c = 0; c < 4; ++c)
            __builtin_amdgcn_global_load_lds(
                (const __attribute__((address_space(1))) void*)(gA + (size_t)c * 32 * DD + k0),
                (__attribute__((address_space(3))) void*)(&As[c * 32 + srow][scol]), 16, 0, 0);
        #pragma unroll
        for (int c = 0; c < 2; ++c)
            __builtin_amdgcn_global_load_lds(
                (const __attribute__((address_space(1))) void*)(gB + (size_t)c * 32 * DD + k0),
                (__attribute__((address_space(3))) void*)(&Bs[c * 32 + srow][scol]), 16, 0, 0);
        __syncthreads();

        #pragma unroll
        for (int ks = 0; ks < 2; ++ks) {
            const int cidx = ((ks * 4 + quad) ^ (l15 & 7)) * 8;
            bf16x8 af[4], bf[2];
            #pragma unroll
            for (int mt = 0; mt < 4; ++mt)
                af[mt] = *(const bf16x8*)&As[wr * 64 + mt * 16 + l15][cidx];
            #pragma unroll
            for (int nt = 0; nt < 2; ++nt)
                bf[nt] = *(const bf16x8*)&Bs[wc * 32 + nt * 16 + l15][cidx];
            #pragma unroll
            for (int mt = 0; mt < 4; ++mt)
                #pragma unroll
                for (int nt = 0; nt < 2; ++nt)
                    acc[mt][nt] = __builtin_amdgcn_mfma_f32_16x16x32_bf16(
                        af[mt], bf[nt], acc[mt][nt], 0, 0, 0);
        }
    }

    #pragma unroll
    for (int mt = 0; mt < 4; ++mt)
        #pragma unroll
        for (int nt = 0; nt < 2; ++nt)
            #pragma unroll
            for (int r = 0; r < 4; ++r)
                C[(size_t)(m0 + wr * 64 + mt * 16 + quad * 4 + r) * DD +
                  (n0 + wc * 32 + nt * 16 + l15)] = acc[mt][nt][r];
}

// ---------------------------------------------------------------------------
// Flash attention, 64-row q-megatile per wave (EXACT round-0 code).
// ---------------------------------------------------------------------------
#define PSTR 72    // bf16 elems per P row (144 B, 16B-aligned, odd*16)
#define OSTR 68    // fp32 elems per Obuf row (col 64 holds the denominator)

__global__ __launch_bounds__(256, 2) void flash_attn(const __bf16* __restrict__ Qp,
                                                     const __bf16* __restrict__ Kp,
                                                     const __bf16* __restrict__ VpT,
                                                     const float* __restrict__ maskadd,
                                                     __bf16* __restrict__ Op)
{
    __shared__ __align__(16) unsigned char smem[4 * 64 * PSTR * 2];
    __bf16 (*Pl)[64][PSTR]  = (__bf16 (*)[64][PSTR])smem;
    float  (*Obuf)[64][OSTR] = (float (*)[64][OSTR])smem;

    const int tid  = threadIdx.x;
    const int lane = tid & 63;
    const int w    = tid >> 6;
    const int l15  = lane & 15;
    const int quad = lane >> 4;
    const int h    = w & 1;                  // kt parity
    const int tile = w >> 1;                 // 0: m=p, 1: m=15-p

    const int bh = blockIdx.x;
    const int hh = bh & (HH - 1);
    const int b  = bh >> 4;
    const int p  = blockIdx.y;               // 0..7
    const int m  = tile ? (15 - p) : p;      // 64-row megatile index

    const size_t hbase = (size_t)b * SS * DD + (size_t)hh * HD;
    const int q0 = m * 64;

    bf16x8 qf[4][2];
    #pragma unroll
    for (int qt = 0; qt < 4; ++qt) {
        const __bf16* qp = Qp + hbase + (size_t)(q0 + qt * 16 + l15) * DD + quad * 8;
        qf[qt][0] = *(const bf16x8*)qp;
        qf[qt][1] = *(const bf16x8*)(qp + 32);
    }

    const __bf16* vt = VpT + (size_t)(hh * HD) * MM + b * SS;
    const float* madd = maskadd + b * SS;

    f32x4 Ov[4][4] = {};
    float lsumq[4] = {};

    for (int kt = h; kt <= m; kt += 2) {
        const int kbase = kt * 64;
        const bool diag = (kt == m);

        f32x4 St[4][4];
        #pragma unroll
        for (int kg = 0; kg < 4; ++kg) {
            const __bf16* kp = Kp + hbase + (size_t)(kbase + kg * 16 + l15) * DD + quad * 8;
            bf16x8 kf0 = *(const bf16x8*)kp;
            bf16x8 kf1 = *(const bf16x8*)(kp + 32);
            #pragma unroll
            for (int qt = 0; qt < 4; ++qt) {
                f32x4 s = {};
                s = __builtin_amdgcn_mfma_f32_16x16x32_bf16(kf0, qf[qt][0], s, 0, 0, 0);
                s = __builtin_amdgcn_mfma_f32_16x16x32_bf16(kf1, qf[qt][1], s, 0, 0, 0);
                St[kg][qt] = s;
            }
        }

        #pragma unroll
        for (int kg = 0; kg < 4; ++kg) {
            const float4 mr = *(const float4*)&madd[kbase + kg * 16 + quad * 4];
            #pragma unroll
            for (int qt = 0; qt < 4; ++qt) {
                const int i = q0 + qt * 16 + l15;
                bf16x4 pk;
                #pragma unroll
                for (int r = 0; r < 4; ++r) {
                    const int j = kbase + kg * 16 + quad * 4 + r;
                    float pv = __expf(St[kg][qt][r] + ((const float*)&mr)[r]);
                    if (diag && j > i) pv = 0.f;
                    lsumq[qt] += pv;
                    pk[r] = (__bf16)pv;
                }
                *(bf16x4*)&Pl[w][qt * 16 + l15][kg * 16 + quad * 4] = pk;
            }
        }

        bf16x8 pf[4][2];
        #pragma unroll
        for (int qt = 0; qt < 4; ++qt) {
            pf[qt][0] = *(const bf16x8*)&Pl[w][qt * 16 + l15][quad * 8];
            pf[qt][1] = *(const bf16x8*)&Pl[w][qt * 16 + l15][quad * 8 + 32];
        }

        #pragma unroll
        for (int dt = 0; dt < 4; ++dt) {
            const __bf16* vp = vt + (size_t)(dt * 16 + l15) * MM + kbase + quad * 8;
            bf16x8 vf0 = *(const bf16x8*)vp;
            bf16x8 vf1 = *(const bf16x8*)(vp + 32);
            #pragma unroll
            for (int qt = 0; qt < 4; ++qt) {
                Ov[qt][dt] = __builtin_amdgcn_mfma_f32_16x16x32_bf16(pf[qt][0], vf0, Ov[qt][dt], 0, 0, 0);
                Ov[qt][dt] = __builtin_amdgcn_mfma_f32_16x16x32_bf16(pf[qt][1], vf1, Ov[qt][dt], 0, 0, 0);
            }
        }
    }

    #pragma unroll
    for (int off = 16; off < 64; off <<= 1)
        #pragma unroll
        for (int qt = 0; qt < 4; ++qt)
            lsumq[qt] += __shfl_xor(lsumq[qt], off);

    __syncthreads();
    if (h == 1) {
        #pragma unroll
        for (int qt = 0; qt < 4; ++qt) {
            #pragma unroll
            for (int dt = 0; dt < 4; ++dt)
                #pragma unroll
                for (int r = 0; r < 4; ++r)
                    Obuf[tile][qt * 16 + quad * 4 + r][dt * 16 + l15] = Ov[qt][dt][r];
            if (quad == 0)
                Obuf[tile][qt * 16 + l15][64] = lsumq[qt];
        }
    }
    __syncthreads();
    if (h == 0) {
        #pragma unroll
        for (int qt = 0; qt < 4; ++qt) {
            const float rcp = 1.0f / (lsumq[qt] + Obuf[tile][qt * 16 + l15][64]);
            float rq[4];
            #pragma unroll
            for (int r = 0; r < 4; ++r) rq[r] = __shfl(rcp, quad * 4 + r);
            #pragma unroll
            for (int dt = 0; dt < 4; ++dt)
                #pragma unroll
                for (int r = 0; r < 4; ++r) {
                    const int i = q0 + qt * 16 + quad * 4 + r;
                    float o = Ov[qt][dt][r] +
                              Obuf[tile][qt * 16 + quad * 4 + r][dt * 16 + l15];
                    Op[hbase + (size_t)i * DD + dt * 16 + l15] = (__bf16)(o * rq[r]);
                }
        }
    }
}

// ---------------------------------------------------------------------------
extern "C" void kernel_launch(void* const* d_in, const int* in_sizes, int n_in,
                              void* d_out, int out_size, void* d_ws, size_t ws_size,
                              hipStream_t stream)
{
    const float* q  = (const float*)d_in[0];
    const float* k  = (const float*)d_in[1];
    const float* v  = (const float*)d_in[2];
    const void*  pm = d_in[3];
    // d_in[4] causal_mask applied analytically
    const float* Wq = (const float*)d_in[5];
    const float* Wk = (const float*)d_in[6];
    const float* Wv = (const float*)d_in[7];
    const float* Wo = (const float*)d_in[8];

    char* ws = (char*)d_ws;
    float* madd = (float*)ws;                  // 16 KB @ 0
    const size_t MB = 1024 * 1024;
    char* base = ws + 65536;

    __bf16* Wqb = (__bf16*)(base +  0 * MB);   // 2 MB each
    __bf16* Wkb = (__bf16*)(base +  2 * MB);
    __bf16* Wvb = (__bf16*)(base +  4 * MB);
    __bf16* Wob = (__bf16*)(base +  6 * MB);
    __bf16* Qp  = (__bf16*)(base +  8 * MB);   // 8 MB each
    __bf16* Kp  = (__bf16*)(base + 16 * MB);
    __bf16* VpT = (__bf16*)(base + 24 * MB);   // transposed [DD][MM]
    __bf16* Op  = (__bf16*)(base + 32 * MB);   // 8 MB

    float* out = (float*)d_out;

    expand_mask<<<(BB * SS) / 256, 256, 0, stream>>>(pm, madd, BB * SS);
    convw<<<dim3(1024, 4), 256, 0, stream>>>(Wq, Wk, Wv, Wo, Wqb, Wkb, Wvb, Wob);

    dim3 gg(MM / GM, DD / GN, 3);  // (32, 16, 3) M-MAJOR
    gemm_qkv<<<gg, 256, 0, stream>>>(q, k, v, Wqb, Wkb, Wvb, Qp, Kp, VpT);

    dim3 ga(BB * HH, 8);           // x = bh (XCD-local), y = megatile pair
    flash_attn<<<ga, 256, 0, stream>>>(Qp, Kp, VpT, madd, Op);

    dim3 gw(MM / GM, DD / GN);     // (32, 16) M-MAJOR
    gemm_wo<<<gw, 256, 0, stream>>>(Op, Wob, out);
}

// Round 6
// 213.335 us; speedup vs baseline: 1.0496x; 1.0496x over previous
//
#include <hip/hip_runtime.h>
#include <hip/hip_bf16.h>

// Problem dims (fixed by reference setup_inputs)
#define BB 4
#define SS 1024
#define DD 1024
#define HH 16
#define HD 64
#define MM (BB*SS)   // 4096 rows

// Session journal:
// Prev session: inputs fp32, out fp32; no-max softmax safe (masked keys
// expf(s-1e9)==0); XOR chunk swizzle kills GEMM LDS bank conflicts.
// R1: 128x128 tile REGRESSED (44.5us) - latency-exposure-bound, not tile-bound.
// R4: dbuf + __syncthreads REGRESSED (47.4us): syncthreads drains vmcnt(0)
//     including the fresh prefetch -> no hiding, +LDS occupancy cost.
// R5: fused fp32 A-staging REGRESSED (64us): 52 VGPR -> loads serialized.
// R6: T4 COUNTED vmcnt. Same R4 dbuf shape, but raw s_barrier + explicit
//     s_waitcnt vmcnt(6): the 6 prefetch loads issued before COMPUTE stay
//     in flight ACROSS the barrier; each wait targets loads issued one full
//     COMPUTE earlier (m218: counted-vs-drain0 = +38-73%; HK-verified asm
//     construction). Everything else = exact round-0 (210.9us baseline).

typedef __bf16 bf16x8 __attribute__((ext_vector_type(8)));
typedef __bf16 bf16x4 __attribute__((ext_vector_type(4)));
typedef float  f32x4  __attribute__((ext_vector_type(4)));

// ---------------------------------------------------------------------------
// Padding mask -> float addend (-1e9 padded, 0 otherwise); format-sniffed.
// ---------------------------------------------------------------------------
__global__ __launch_bounds__(256) void expand_mask(const void* __restrict__ pmraw,
                                                   float* __restrict__ madd,
                                                   int n)
{
    const unsigned char* bytes = (const unsigned char*)pmraw;
    __shared__ int isbool;
    if (threadIdx.x == 0) isbool = 0;
    __syncthreads();
    int flag = 0;
    for (int idx = threadIdx.x; idx < n; idx += 256) {
        if ((idx & 3) && bytes[idx]) flag = 1;
    }
    if (flag) atomicOr(&isbool, 1);
    __syncthreads();
    int i = blockIdx.x * 256 + threadIdx.x;
    if (i < n) {
        int v = isbool ? (int)bytes[i] : ((const int*)pmraw)[i];
        madd[i] = (v != 0) ? -1e9f : 0.0f;
    }
}

// ---------------------------------------------------------------------------
// One-launch fp32->bf16 convert of q,k,v (y=0..2) and Wq/Wk/Wv/Wo (y=3).
// ---------------------------------------------------------------------------
__global__ __launch_bounds__(256) void convall(const float* __restrict__ q,
                                               const float* __restrict__ k,
                                               const float* __restrict__ v,
                                               const float* __restrict__ Wq,
                                               const float* __restrict__ Wk,
                                               const float* __restrict__ Wv,
                                               const float* __restrict__ Wo,
                                               __bf16* __restrict__ qb,
                                               __bf16* __restrict__ kb,
                                               __bf16* __restrict__ vb,
                                               __bf16* __restrict__ Wqb,
                                               __bf16* __restrict__ Wkb,
                                               __bf16* __restrict__ Wvb,
                                               __bf16* __restrict__ Wob)
{
    const float* s; __bf16* d; int i;
    if (blockIdx.y < 3) {
        if (blockIdx.y == 0)      { s = q; d = qb; }
        else if (blockIdx.y == 1) { s = k; d = kb; }
        else                      { s = v; d = vb; }
        i = (blockIdx.x * 256 + threadIdx.x) * 4;
    } else {
        const int wsel = blockIdx.x >> 10;        // 1024 blocks per weight
        const int lx   = blockIdx.x & 1023;
        if (wsel == 0)      { s = Wq; d = Wqb; }
        else if (wsel == 1) { s = Wk; d = Wkb; }
        else if (wsel == 2) { s = Wv; d = Wvb; }
        else                { s = Wo; d = Wob; }
        i = (lx * 256 + threadIdx.x) * 4;
    }
    float4 x = *(const float4*)(s + i);
    bf16x4 o;
    o[0] = (__bf16)x.x; o[1] = (__bf16)x.y;
    o[2] = (__bf16)x.z; o[3] = (__bf16)x.w;
    *(bf16x4*)(d + i) = o;
}

// ---------------------------------------------------------------------------
// Fused QKV MFMA GEMM, 128x64 tile, BK=64, M-major grid, XOR-swizzled LDS,
// double-buffered with COUNTED vmcnt: STAGE(next) issued BEFORE COMPUTE(cur);
// raw s_barrier (no implicit drain) + s_waitcnt vmcnt(6) lets the 6 fresh
// prefetch loads fly across the barrier; the wait only drains the 6 loads
// issued one COMPUTE phase earlier. 2 barriers per K-step (reuse guard +
// data-ready), all in uniform control flow.
// z==0 (Q): prescale 0.125. z==2 (V): store transposed VpT[n][m] (stride MM).
// ---------------------------------------------------------------------------
#define GM 128
#define GN 64
#define GK 64
#define KSTEPS (DD / GK)   // 16

#define WAITV6() asm volatile("s_waitcnt vmcnt(6)")
#define WAITV0() asm volatile("s_waitcnt vmcnt(0)")
#define BARX()   asm volatile("s_barrier" ::: "memory")

#define STAGE(As, Bs, buf, k0)                                                          \
    {                                                                                   \
        _Pragma("unroll")                                                               \
        for (int c = 0; c < 4; ++c)                                                     \
            __builtin_amdgcn_global_load_lds(                                           \
                (const __attribute__((address_space(1))) void*)(gA + (size_t)c * 32 * DD + (k0)), \
                (__attribute__((address_space(3))) void*)(&As[buf][c * 32 + srow][scol]), 16, 0, 0); \
        _Pragma("unroll")                                                               \
        for (int c = 0; c < 2; ++c)                                                     \
            __builtin_amdgcn_global_load_lds(                                           \
                (const __attribute__((address_space(1))) void*)(gB + (size_t)c * 32 * DD + (k0)), \
                (__attribute__((address_space(3))) void*)(&Bs[buf][c * 32 + srow][scol]), 16, 0, 0); \
    }

#define COMPUTE(As, Bs, buf)                                                            \
    {                                                                                   \
        _Pragma("unroll")                                                               \
        for (int ks = 0; ks < 2; ++ks) {                                                \
            const int cidx = ((ks * 4 + quad) ^ (l15 & 7)) * 8;                         \
            bf16x8 af[4], bf[2];                                                        \
            _Pragma("unroll")                                                           \
            for (int mt = 0; mt < 4; ++mt)                                              \
                af[mt] = *(const bf16x8*)&As[buf][wr * 64 + mt * 16 + l15][cidx];       \
            _Pragma("unroll")                                                           \
            for (int nt = 0; nt < 2; ++nt)                                              \
                bf[nt] = *(const bf16x8*)&Bs[buf][wc * 32 + nt * 16 + l15][cidx];       \
            _Pragma("unroll")                                                           \
            for (int mt = 0; mt < 4; ++mt)                                              \
                _Pragma("unroll")                                                       \
                for (int nt = 0; nt < 2; ++nt)                                          \
                    acc[mt][nt] = __builtin_amdgcn_mfma_f32_16x16x32_bf16(              \
                        af[mt], bf[nt], acc[mt][nt], 0, 0, 0);                          \
        }                                                                               \
    }

// Counted-vmcnt dbuf K-loop, shared by both GEMMs.
// Steady state: each WAITV6 drains the 6 loads issued one COMPUTE earlier.
#define KLOOP(As, Bs)                                                                   \
    STAGE(As, Bs, 0, 0);                                                                \
    for (int t = 0; t < KSTEPS; t += 2) {                                               \
        STAGE(As, Bs, 1, (t + 1) * GK);                                                 \
        WAITV6();                                                                       \
        BARX();                                                                         \
        COMPUTE(As, Bs, 0);                                                             \
        BARX();                                                                         \
        if (t + 2 < KSTEPS) {                                                           \
            STAGE(As, Bs, 0, (t + 2) * GK);                                             \
            WAITV6();                                                                   \
        } else {                                                                        \
            WAITV0();                                                                   \
        }                                                                               \
        BARX();                                                                         \
        COMPUTE(As, Bs, 1);                                                             \
        BARX();                                                                         \
    }

__global__ __launch_bounds__(256) void gemm_qkv(const __bf16* __restrict__ qb,
                                                const __bf16* __restrict__ kb,
                                                const __bf16* __restrict__ vb,
                                                const __bf16* __restrict__ Wqb,
                                                const __bf16* __restrict__ Wkb,
                                                const __bf16* __restrict__ Wvb,
                                                __bf16* __restrict__ Qp,
                                                __bf16* __restrict__ Kp,
                                                __bf16* __restrict__ VpT)
{
    __shared__ __align__(16) __bf16 As[2][GM][GK];   // 32 KB
    __shared__ __align__(16) __bf16 Bs[2][GN][GK];   // 16 KB

    const __bf16 *A, *W; __bf16* C;
    const int z = blockIdx.z;
    if (z == 0)      { A = qb; W = Wqb; C = Qp;  }
    else if (z == 1) { A = kb; W = Wkb; C = Kp;  }
    else             { A = vb; W = Wvb; C = VpT; }

    const int tid  = threadIdx.x;
    const int lane = tid & 63;
    const int w    = tid >> 6;
    const int l15  = lane & 15;
    const int quad = lane >> 4;
    const int wr   = w >> 1;
    const int wc   = w & 1;

    const int m0 = blockIdx.x * GM;    // M-MAJOR: x is the m-tile
    const int n0 = blockIdx.y * GN;

    const int srow = tid >> 3;                       // 0..31
    const int scol = (tid & 7) * 8;                  // LDS column (lane-linear)
    const int gcol = (((tid & 7) ^ (srow & 7)) * 8); // swizzled GLOBAL column

    const __bf16* gA = A + (size_t)(m0 + srow) * DD + gcol;
    const __bf16* gB = W + (size_t)(n0 + srow) * DD + gcol;

    f32x4 acc[4][2] = {};

    KLOOP(As, Bs);

    if (z == 0) {
        #pragma unroll
        for (int mt = 0; mt < 4; ++mt)
            #pragma unroll
            for (int nt = 0; nt < 2; ++nt)
                #pragma unroll
                for (int r = 0; r < 4; ++r)
                    acc[mt][nt][r] *= 0.125f;     // fold softmax scale into Q
    }

    if (z == 2) {
        #pragma unroll
        for (int mt = 0; mt < 4; ++mt)
            #pragma unroll
            for (int nt = 0; nt < 2; ++nt) {
                bf16x4 o;
                #pragma unroll
                for (int r = 0; r < 4; ++r) o[r] = (__bf16)acc[mt][nt][r];
                const int n = n0 + wc * 32 + nt * 16 + l15;
                const int m = m0 + wr * 64 + mt * 16 + quad * 4;
                *(bf16x4*)&C[(size_t)n * MM + m] = o;
            }
    } else {
        #pragma unroll
        for (int mt = 0; mt < 4; ++mt)
            #pragma unroll
            for (int nt = 0; nt < 2; ++nt)
                #pragma unroll
                for (int r = 0; r < 4; ++r)
                    C[(size_t)(m0 + wr * 64 + mt * 16 + quad * 4 + r) * DD +
                      (n0 + wc * 32 + nt * 16 + l15)] = (__bf16)acc[mt][nt][r];
    }
}

// ---------------------------------------------------------------------------
// Wo GEMM: same counted-vmcnt dbuf 128x64/BK=64 structure, fp32 out, M-major.
// ---------------------------------------------------------------------------
__global__ __launch_bounds__(256) void gemm_wo(const __bf16* __restrict__ Ain,
                                               const __bf16* __restrict__ W,
                                               float* __restrict__ C)
{
    __shared__ __align__(16) __bf16 As[2][GM][GK];   // 32 KB
    __shared__ __align__(16) __bf16 Bs[2][GN][GK];   // 16 KB

    const int tid  = threadIdx.x;
    const int lane = tid & 63;
    const int w    = tid >> 6;
    const int l15  = lane & 15;
    const int quad = lane >> 4;
    const int wr   = w >> 1;
    const int wc   = w & 1;

    const int m0 = blockIdx.x * GM;    // M-MAJOR
    const int n0 = blockIdx.y * GN;

    const int srow = tid >> 3;
    const int scol = (tid & 7) * 8;
    const int gcol = (((tid & 7) ^ (srow & 7)) * 8);

    const __bf16* gA = Ain + (size_t)(m0 + srow) * DD + gcol;
    const __bf16* gB = W   + (size_t)(n0 + srow) * DD + gcol;

    f32x4 acc[4][2] = {};

    KLOOP(As, Bs);

    #pragma unroll
    for (int mt = 0; mt < 4; ++mt)
        #pragma unroll
        for (int nt = 0; nt < 2; ++nt)
            #pragma unroll
            for (int r = 0; r < 4; ++r)
                C[(size_t)(m0 + wr * 64 + mt * 16 + quad * 4 + r) * DD +
                  (n0 + wc * 32 + nt * 16 + l15)] = acc[mt][nt][r];
}

// ---------------------------------------------------------------------------
// Flash attention, 64-row q-megatile per wave (EXACT round-0 code).
// ---------------------------------------------------------------------------
#define PSTR 72    // bf16 elems per P row (144 B, 16B-aligned, odd*16)
#define OSTR 68    // fp32 elems per Obuf row (col 64 holds the denominator)

__global__ __launch_bounds__(256, 2) void flash_attn(const __bf16* __restrict__ Qp,
                                                     const __bf16* __restrict__ Kp,
                                                     const __bf16* __restrict__ VpT,
                                                     const float* __restrict__ maskadd,
                                                     __bf16* __restrict__ Op)
{
    __shared__ __align__(16) unsigned char smem[4 * 64 * PSTR * 2];
    __bf16 (*Pl)[64][PSTR]  = (__bf16 (*)[64][PSTR])smem;
    float  (*Obuf)[64][OSTR] = (float (*)[64][OSTR])smem;

    const int tid  = threadIdx.x;
    const int lane = tid & 63;
    const int w    = tid >> 6;
    const int l15  = lane & 15;
    const int quad = lane >> 4;
    const int h    = w & 1;                  // kt parity
    const int tile = w >> 1;                 // 0: m=p, 1: m=15-p

    const int bh = blockIdx.x;
    const int hh = bh & (HH - 1);
    const int b  = bh >> 4;
    const int p  = blockIdx.y;               // 0..7
    const int m  = tile ? (15 - p) : p;      // 64-row megatile index

    const size_t hbase = (size_t)b * SS * DD + (size_t)hh * HD;
    const int q0 = m * 64;

    bf16x8 qf[4][2];
    #pragma unroll
    for (int qt = 0; qt < 4; ++qt) {
        const __bf16* qp = Qp + hbase + (size_t)(q0 + qt * 16 + l15) * DD + quad * 8;
        qf[qt][0] = *(const bf16x8*)qp;
        qf[qt][1] = *(const bf16x8*)(qp + 32);
    }

    const __bf16* vt = VpT + (size_t)(hh * HD) * MM + b * SS;
    const float* madd = maskadd + b * SS;

    f32x4 Ov[4][4] = {};
    float lsumq[4] = {};

    for (int kt = h; kt <= m; kt += 2) {
        const int kbase = kt * 64;
        const bool diag = (kt == m);

        f32x4 St[4][4];
        #pragma unroll
        for (int kg = 0; kg < 4; ++kg) {
            const __bf16* kp = Kp + hbase + (size_t)(kbase + kg * 16 + l15) * DD + quad * 8;
            bf16x8 kf0 = *(const bf16x8*)kp;
            bf16x8 kf1 = *(const bf16x8*)(kp + 32);
            #pragma unroll
            for (int qt = 0; qt < 4; ++qt) {
                f32x4 s = {};
                s = __builtin_amdgcn_mfma_f32_16x16x32_bf16(kf0, qf[qt][0], s, 0, 0, 0);
                s = __builtin_amdgcn_mfma_f32_16x16x32_bf16(kf1, qf[qt][1], s, 0, 0, 0);
                St[kg][qt] = s;
            }
        }

        #pragma unroll
        for (int kg = 0; kg < 4; ++kg) {
            const float4 mr = *(const float4*)&madd[kbase + kg * 16 + quad * 4];
            #pragma unroll
            for (int qt = 0; qt < 4; ++qt) {
                const int i = q0 + qt * 16 + l15;
                bf16x4 pk;
                #pragma unroll
                for (int r = 0; r < 4; ++r) {
                    const int j = kbase + kg * 16 + quad * 4 + r;
                    float pv = __expf(St[kg][qt][r] + ((const float*)&mr)[r]);
                    if (diag && j > i) pv = 0.f;
                    lsumq[qt] += pv;
                    pk[r] = (__bf16)pv;
                }
                *(bf16x4*)&Pl[w][qt * 16 + l15][kg * 16 + quad * 4] = pk;
            }
        }

        bf16x8 pf[4][2];
        #pragma unroll
        for (int qt = 0; qt < 4; ++qt) {
            pf[qt][0] = *(const bf16x8*)&Pl[w][qt * 16 + l15][quad * 8];
            pf[qt][1] = *(const bf16x8*)&Pl[w][qt * 16 + l15][quad * 8 + 32];
        }

        #pragma unroll
        for (int dt = 0; dt < 4; ++dt) {
            const __bf16* vp = vt + (size_t)(dt * 16 + l15) * MM + kbase + quad * 8;
            bf16x8 vf0 = *(const bf16x8*)vp;
            bf16x8 vf1 = *(const bf16x8*)(vp + 32);
            #pragma unroll
            for (int qt = 0; qt < 4; ++qt) {
                Ov[qt][dt] = __builtin_amdgcn_mfma_f32_16x16x32_bf16(pf[qt][0], vf0, Ov[qt][dt], 0, 0, 0);
                Ov[qt][dt] = __builtin_amdgcn_mfma_f32_16x16x32_bf16(pf[qt][1], vf1, Ov[qt][dt], 0, 0, 0);
            }
        }
    }

    #pragma unroll
    for (int off = 16; off < 64; off <<= 1)
        #pragma unroll
        for (int qt = 0; qt < 4; ++qt)
            lsumq[qt] += __shfl_xor(lsumq[qt], off);

    __syncthreads();
    if (h == 1) {
        #pragma unroll
        for (int qt = 0; qt < 4; ++qt) {
            #pragma unroll
            for (int dt = 0; dt < 4; ++dt)
                #pragma unroll
                for (int r = 0; r < 4; ++r)
                    Obuf[tile][qt * 16 + quad * 4 + r][dt * 16 + l15] = Ov[qt][dt][r];
            if (quad == 0)
                Obuf[tile][qt * 16 + l15][64] = lsumq[qt];
        }
    }
    __syncthreads();
    if (h == 0) {
        #pragma unroll
        for (int qt = 0; qt < 4; ++qt) {
            const float rcp = 1.0f / (lsumq[qt] + Obuf[tile][qt * 16 + l15][64]);
            float rq[4];
            #pragma unroll
            for (int r = 0; r < 4; ++r) rq[r] = __shfl(rcp, quad * 4 + r);
            #pragma unroll
            for (int dt = 0; dt < 4; ++dt)
                #pragma unroll
                for (int r = 0; r < 4; ++r) {
                    const int i = q0 + qt * 16 + quad * 4 + r;
                    float o = Ov[qt][dt][r] +
                              Obuf[tile][qt * 16 + quad * 4 + r][dt * 16 + l15];
                    Op[hbase + (size_t)i * DD + dt * 16 + l15] = (__bf16)(o * rq[r]);
                }
        }
    }
}

// ---------------------------------------------------------------------------
extern "C" void kernel_launch(void* const* d_in, const int* in_sizes, int n_in,
                              void* d_out, int out_size, void* d_ws, size_t ws_size,
                              hipStream_t stream)
{
    const float* q  = (const float*)d_in[0];
    const float* k  = (const float*)d_in[1];
    const float* v  = (const float*)d_in[2];
    const void*  pm = d_in[3];
    // d_in[4] causal_mask applied analytically
    const float* Wq = (const float*)d_in[5];
    const float* Wk = (const float*)d_in[6];
    const float* Wv = (const float*)d_in[7];
    const float* Wo = (const float*)d_in[8];

    char* ws = (char*)d_ws;
    float* madd = (float*)ws;                  // 16 KB @ 0
    const size_t MB = 1024 * 1024;
    char* base = ws + 65536;

    __bf16* qb  = (__bf16*)(base +  0 * MB);   // 8 MB
    __bf16* kb  = (__bf16*)(base +  8 * MB);   // 8 MB
    __bf16* vb  = (__bf16*)(base + 16 * MB);   // 8 MB
    __bf16* Wqb = (__bf16*)(base + 24 * MB);   // 2 MB
    __bf16* Wkb = (__bf16*)(base + 26 * MB);
    __bf16* Wvb = (__bf16*)(base + 28 * MB);
    __bf16* Wob = (__bf16*)(base + 30 * MB);
    __bf16* Qp  = (__bf16*)(base + 32 * MB);   // 8 MB
    __bf16* Kp  = (__bf16*)(base + 40 * MB);
    __bf16* VpT = (__bf16*)(base + 48 * MB);   // 8 MB, transposed [DD][MM]
    __bf16* Op  = qb;                          // reuse (qb dead after gemm_qkv)

    float* out = (float*)d_out;
    const int NT = MM * DD;     // 4M

    expand_mask<<<(BB * SS) / 256, 256, 0, stream>>>(pm, madd, BB * SS);
    convall<<<dim3(NT / 1024, 4), 256, 0, stream>>>(q, k, v, Wq, Wk, Wv, Wo,
                                                    qb, kb, vb, Wqb, Wkb, Wvb, Wob);

    dim3 gg(MM / GM, DD / GN, 3);  // (32, 16, 3) M-MAJOR
    gemm_qkv<<<gg, 256, 0, stream>>>(qb, kb, vb, Wqb, Wkb, Wvb, Qp, Kp, VpT);

    dim3 ga(BB * HH, 8);           // x = bh (XCD-local), y = megatile pair
    flash_attn<<<ga, 256, 0, stream>>>(Qp, Kp, VpT, madd, Op);

    dim3 gw(MM / GM, DD / GN);     // (32, 16) M-MAJOR
    gemm_wo<<<gw, 256, 0, stream>>>(Op, Wob, out);
}